// Round 6
// baseline (231.408 us; speedup 1.0000x reference)
//
#include <hip/hip_runtime.h>

constexpr int B = 2, C = 64, H = 112, W = 112;
constexpr int HW = H * W;          // 12544
constexpr int NPIX = B * HW;       // 25088
constexpr int TILES_X = 14;
constexpr int TILES_PER_IMG = 196;
constexpr int NBLK = B * TILES_PER_IMG;   // 392
constexpr float EPS_LN = 1e-6f, EPS_NORM = 1e-7f;

__device__ __forceinline__ float rcp_fast(float x) { return __builtin_amdgcn_rcpf(x); }
__device__ __forceinline__ float sigmoid_f(float x) { return rcp_fast(1.f + __expf(-x)); }
// Force wave-uniformity so the compiler emits s_load for weight rows.
__device__ __forceinline__ int uni(int x) { return __builtin_amdgcn_readfirstlane(x); }

// ---------------------------------------------------------------------------
// k1: px = range_proj(semantic). 512 threads / 8x8 tile; 8 waves split the 64
// output channels (8 each). lane = pixel. Weights via scalar loads (uniform o).
// ---------------------------------------------------------------------------
__global__ __launch_bounds__(512, 2) void k1_range_proj(
    const float* __restrict__ sem,
    const float* __restrict__ w1, const float* __restrict__ b1,
    const float* __restrict__ g,  const float* __restrict__ be,
    const float* __restrict__ w2, const float* __restrict__ b2,
    float* __restrict__ px_t, float* __restrict__ sqnorm)
{
    __shared__ float f_scr[64 * 64];    // [o][pix]
    __shared__ float px_scr[64 * 65];   // [o][pix] pitch 65 (transpose-out)
    __shared__ float pm[8 * 64], ps[8 * 64], p2[8 * 64];

    const int tid = threadIdx.x, lane = tid & 63, wv = tid >> 6;
    const int blk = blockIdx.x, b = blk / TILES_PER_IMG, t = blk - b * TILES_PER_IMG;
    const int ty = t / TILES_X, tx = t - ty * TILES_X;
    const int h = ty * 8 + (lane >> 3), w = tx * 8 + (lane & 7);
    const int hw = h * W + w;

    float sv[64];
#pragma unroll
    for (int k = 0; k < 64; ++k) sv[k] = sem[(size_t)(b * 64 + k) * HW + hw];

    const int o0 = uni(wv * 8);
    float macc = 0.f, sacc = 0.f;
    for (int j = 0; j < 8; ++j) {
        const int o = o0 + j;                 // uniform
        const float* wr = &w1[o * 64];
        float a0 = 0, a1 = 0, a2 = 0, a3 = 0;
#pragma unroll
        for (int k = 0; k < 64; k += 4) {
            a0 += wr[k] * sv[k];       a1 += wr[k + 1] * sv[k + 1];
            a2 += wr[k + 2] * sv[k + 2]; a3 += wr[k + 3] * sv[k + 3];
        }
        float f = (a0 + a1) + (a2 + a3) + b1[o];
        f_scr[o * 64 + lane] = f;      // bank=lane%32: 2-way, free
        macc += f; sacc += f * f;
    }
    pm[wv * 64 + lane] = macc; ps[wv * 64 + lane] = sacc;
    __syncthreads();
    float msum = 0.f, ssum = 0.f;
#pragma unroll
    for (int j = 0; j < 8; ++j) { msum += pm[j * 64 + lane]; ssum += ps[j * 64 + lane]; }
    float m  = msum * (1.f / 64.f);
    float va = ssum * (1.f / 64.f) - m * m;
    float rstd = rsqrtf(va + EPS_LN);

    float s[64];
#pragma unroll
    for (int k = 0; k < 64; ++k) {
        float y = g[k] * (f_scr[k * 64 + lane] - m) * rstd + be[k];
        s[k] = y * sigmoid_f(y);
    }
    float sq = 0.f;
    for (int j = 0; j < 8; ++j) {
        const int o = o0 + j;                 // uniform
        const float* wr = &w2[o * 64];
        float a0 = 0, a1 = 0, a2 = 0, a3 = 0;
#pragma unroll
        for (int k = 0; k < 64; k += 4) {
            a0 += wr[k] * s[k];        a1 += wr[k + 1] * s[k + 1];
            a2 += wr[k + 2] * s[k + 2]; a3 += wr[k + 3] * s[k + 3];
        }
        float z = (a0 + a1) + (a2 + a3) + b2[o];
        px_scr[o * 65 + lane] = z;     // bank=(o+lane)%32: conflict-free
        sq += z * z;
    }
    p2[wv * 64 + lane] = sq;
    __syncthreads();
    if (wv == 0) {
        float q = 0.f;
#pragma unroll
        for (int j = 0; j < 8; ++j) q += p2[j * 64 + lane];
        sqnorm[(size_t)b * HW + hw] = q;
    }
    // transpose-out: wave wv stores pixels o0..o0+7; lane = channel
    for (int j = 0; j < 8; ++j) {
        int ii = o0 + j;
        int hwi = (ty * 8 + (ii >> 3)) * W + tx * 8 + (ii & 7);
        px_t[((size_t)b * HW + hwi) * 64 + lane] = px_scr[lane * 65 + ii];  // (lane+ii)%32: cf
    }
}

// ---------------------------------------------------------------------------
// k23: fused bilateral weights + gated fixup + normalize + neighborhood
// reduction + output_proj. 512 threads / 8x8 tile. Weights via scalar loads.
// Halo layout: element (r, c) at (r<<6) | (c ^ ((r&7)<<2)) -> b128 accesses at
// the 1KB/128B LDS floor.
// ---------------------------------------------------------------------------
__global__ __launch_bounds__(512, 2) void k23_fused(
    const float* __restrict__ px_t, const float* __restrict__ sqnorm,
    const float* __restrict__ sem,  const float* __restrict__ spat,
    const float* __restrict__ fw1, const float* __restrict__ fb1,
    const float* __restrict__ fg,  const float* __restrict__ fbe,
    const float* __restrict__ fw2, const float* __restrict__ fb2,
    const float* __restrict__ w1, const float* __restrict__ b1,
    const float* __restrict__ g,  const float* __restrict__ be,
    const float* __restrict__ w2, const float* __restrict__ b2,
    const float* __restrict__ sigma_, float* __restrict__ out)
{
    __shared__ __align__(16) float halo[196 * 64];      // 50176 B (aliased below)
    __shared__ __align__(16) float comb_scr[49 * 64];   // 12544 B
    __shared__ float sqn_l[196];
    __shared__ float pm[8 * 64], ps[8 * 64], pt[8 * 64];

    const int tid = threadIdx.x, lane = tid & 63, wv = tid >> 6;
    const int blk = blockIdx.x, b = blk / TILES_PER_IMG, t = blk - b * TILES_PER_IMG;
    const int ty = t / TILES_X, tx = t - ty * TILES_X;
    const int h = ty * 8 + (lane >> 3), w = tx * 8 + (lane & 7);
    const int hw = h * W + w;
    const int h0 = ty * 8 - 3, w0 = tx * 8 - 3;

    // ---- phase 1: stage px halo (pixel-major source: coalesced, cf writes) ----
    for (int i = 0; i < 25; ++i) {
        int idx = i * 512 + tid;
        if (idx < 12544) {
            int r = idx >> 6, c = idx & 63;
            int ry = (r * 2341) >> 15, rx = r - ry * 14;     // exact /14 for r<256
            int hh = h0 + ry, ww = w0 + rx;
            bool valid = (unsigned)hh < (unsigned)H && (unsigned)ww < (unsigned)W;
            float v = 0.f;
            if (valid) v = px_t[((size_t)b * HW + hh * W + ww) * 64 + c];
            halo[(r << 6) | (c ^ ((r & 7) << 2))] = v;
        }
    }
    if (tid < 196) {
        int ry = (tid * 2341) >> 15, rx = tid - ry * 14;
        int hh = h0 + ry, ww = w0 + rx;
        bool valid = (unsigned)hh < (unsigned)H && (unsigned)ww < (unsigned)W;
        float v = 0.f;
        if (valid) v = sqnorm[(size_t)b * HW + hh * W + ww];
        sqn_l[tid] = v;
    }
    __syncthreads();

    // ---- phase 2: bilateral weights, neighbors split across 8 waves ----
    const int rbase = (lane >> 3) * 14 + (lane & 7);
    const int rp = rbase + 45;
    const int ctr = (rp << 6) ^ ((rp & 7) << 2);
    float cv[64];
#pragma unroll
    for (int q = 0; q < 16; ++q) {
        float4 v = *(const float4*)&halo[ctr ^ (q << 2)];
        cv[4 * q] = v.x; cv[4 * q + 1] = v.y; cv[4 * q + 2] = v.z; cv[4 * q + 3] = v.w;
    }
    const float sqc = sqn_l[rp];
    const float sg_ = sigma_[0];
    const float inv2s2 = rcp_fast(2.f * sg_ * sg_);
    for (int i = 0; i < 7; ++i) {
        int n = uni(wv + 8 * i);
        if (n < 49) {
            int ryn = n / 7, rxn = n - ryn * 7;
            int dy = ryn - 3, dx = rxn - 3;
            int rn = rbase + ryn * 14 + rxn;
            int bx = (rn << 6) ^ ((rn & 7) << 2);
            float d0 = 0, d1 = 0, d2 = 0, d3 = 0;
#pragma unroll
            for (int q = 0; q < 16; ++q) {
                float4 v = *(const float4*)&halo[bx ^ (q << 2)];
                d0 += v.x * cv[4 * q];     d1 += v.y * cv[4 * q + 1];
                d2 += v.z * cv[4 * q + 2]; d3 += v.w * cv[4 * q + 3];
            }
            float dot = (d0 + d1) + (d2 + d3);
            float dist2 = fmaxf(sqn_l[rn] + sqc - 2.f * dot, 0.f);
            bool valid = (unsigned)(h + dy) < (unsigned)H && (unsigned)(w + dx) < (unsigned)W;
            float d2n = (float)(dy * dy + dx * dx);
            comb_scr[n * 64 + lane] = valid ? __expf(-(dist2 * (1.f / 128.f) + d2n * inv2s2)) : 0.f;
        }
    }
    __syncthreads();

    // ---- phase 3: gated fixup, outputs split across 8 waves ----
    float cb[49];
#pragma unroll
    for (int n = 0; n < 49; ++n) cb[n] = comb_scr[n * 64 + lane];
    float svv[64];
#pragma unroll
    for (int k = 0; k < 64; ++k) svv[k] = sem[(size_t)(b * 64 + k) * HW + hw];
    float* f_scr = halo;                 // px halo dead after phase 2
    float macc = 0.f, sacc = 0.f;
    for (int i = 0; i < 7; ++i) {
        const int o = uni(wv + 8 * i);   // uniform -> s_load weight row
        if (o < 49) {
            const float* wr = &fw1[o * 113];
            float a0 = 0, a1 = 0, a2 = 0, a3 = 0;
#pragma unroll
            for (int k = 0; k < 48; k += 4) {
                a0 += wr[k] * cb[k];       a1 += wr[k + 1] * cb[k + 1];
                a2 += wr[k + 2] * cb[k + 2]; a3 += wr[k + 3] * cb[k + 3];
            }
            a0 += wr[48] * cb[48];
            const float* wr2 = wr + 49;
#pragma unroll
            for (int k = 0; k < 64; k += 4) {
                a0 += wr2[k] * svv[k];       a1 += wr2[k + 1] * svv[k + 1];
                a2 += wr2[k + 2] * svv[k + 2]; a3 += wr2[k + 3] * svv[k + 3];
            }
            float f = (a0 + a1) + (a2 + a3) + fb1[o];
            f_scr[o * 64 + lane] = f;
            macc += f; sacc += f * f;
        }
    }
    pm[wv * 64 + lane] = macc; ps[wv * 64 + lane] = sacc;
    __syncthreads();
    {
        float msum = 0.f, ssum = 0.f;
#pragma unroll
        for (int j = 0; j < 8; ++j) { msum += pm[j * 64 + lane]; ssum += ps[j * 64 + lane]; }
        float m  = msum * (1.f / 49.f);
        float va = ssum * (1.f / 49.f) - m * m;
        float rstd = rsqrtf(va + EPS_LN);
        float s[49];
#pragma unroll
        for (int k = 0; k < 49; ++k) {
            float y = fg[k] * (f_scr[k * 64 + lane] - m) * rstd + fbe[k];
            s[k] = y * sigmoid_f(y);
        }
        float tacc = 0.f;
        for (int i = 0; i < 7; ++i) {
            const int o = uni(wv + 8 * i);
            if (o < 49) {
                const float* wr = &fw2[o * 49];
                float a0 = 0, a1 = 0, a2 = 0, a3 = 0;
#pragma unroll
                for (int k = 0; k < 48; k += 4) {
                    a0 += wr[k] * s[k];       a1 += wr[k + 1] * s[k + 1];
                    a2 += wr[k + 2] * s[k + 2]; a3 += wr[k + 3] * s[k + 3];
                }
                a0 += wr[48] * s[48];
                float fo = (a0 + a1) + (a2 + a3) + fb2[o];
                float gate = 1.f + sigmoid_f(fo);
                float cx = comb_scr[o * 64 + lane] * gate;
                comb_scr[o * 64 + lane] = cx;
                tacc += cx;
            }
        }
        pt[wv * 64 + lane] = tacc;
    }
    __syncthreads();   // all f_scr reads done -> halo restage is safe
    float tsum = 0.f;
#pragma unroll
    for (int j = 0; j < 8; ++j) tsum += pt[j * 64 + lane];
    const float inv = rcp_fast(tsum + EPS_NORM);

    // ---- phase 4: restage halo with spatial (channel-major source) ----
    // quad-per-thread: 4 coalesced b32 loads + one b128 swizzled write.
    for (int i = 0; i < 7; ++i) {
        int idx = i * 512 + tid;          // idx = cq*196 + r
        if (idx < 3136) {
            int cq = idx / 196, r = idx - cq * 196;
            int ry = (r * 2341) >> 15, rx = r - ry * 14;
            int hh = h0 + ry, ww = w0 + rx;
            bool valid = (unsigned)hh < (unsigned)H && (unsigned)ww < (unsigned)W;
            float4 v = make_float4(0.f, 0.f, 0.f, 0.f);
            if (valid) {
                const float* sp = &spat[(size_t)(b * 64 + cq * 4) * HW + hh * W + ww];
                v.x = sp[0]; v.y = sp[HW]; v.z = sp[2 * HW]; v.w = sp[3 * HW];
            }
            *(float4*)&halo[(r << 6) | ((cq ^ (r & 7)) << 2)] = v;
        }
    }
    __syncthreads();

    // ---- phase 5: weighted neighborhood reduction, 8 channels per wave ----
    const int c0 = uni(wv * 8);
    float acc[8];
#pragma unroll
    for (int j = 0; j < 8; ++j) acc[j] = 0.f;
    for (int n = 0; n < 49; ++n) {
        int ryn = n / 7, rxn = n - ryn * 7;
        int rn = rbase + ryn * 14 + rxn;
        int bx = (rn << 6) ^ ((rn & 7) << 2);
        float cn = comb_scr[n * 64 + lane] * inv;
#pragma unroll
        for (int q = 0; q < 2; ++q) {
            float4 v = *(const float4*)&halo[bx ^ (((c0 >> 2) + q) << 2)];
            acc[4 * q]     += cn * v.x; acc[4 * q + 1] += cn * v.y;
            acc[4 * q + 2] += cn * v.z; acc[4 * q + 3] += cn * v.w;
        }
    }
    __syncthreads();   // halo reads done -> av/f2 aliases safe

    // ---- phase 6: output_proj ----
    float* av = halo;                 // [c][pix] 64x64
    float* f2 = halo + 4096;          // [o][pix] 64x64
    for (int j = 0; j < 8; ++j) av[(c0 + j) * 64 + lane] = acc[j];
    __syncthreads();
    float xv[64];
#pragma unroll
    for (int k = 0; k < 64; ++k) xv[k] = av[k * 64 + lane];
    float macc2 = 0.f, sacc2 = 0.f;
    for (int j = 0; j < 8; ++j) {
        const int o = c0 + j;             // uniform
        const float* wr = &w1[o * 64];
        float a0 = 0, a1 = 0, a2 = 0, a3 = 0;
#pragma unroll
        for (int k = 0; k < 64; k += 4) {
            a0 += wr[k] * xv[k];       a1 += wr[k + 1] * xv[k + 1];
            a2 += wr[k + 2] * xv[k + 2]; a3 += wr[k + 3] * xv[k + 3];
        }
        float f = (a0 + a1) + (a2 + a3) + b1[o];
        f2[o * 64 + lane] = f;
        macc2 += f; sacc2 += f * f;
    }
    pm[wv * 64 + lane] = macc2; ps[wv * 64 + lane] = sacc2;
    __syncthreads();
    float msum2 = 0.f, ssum2 = 0.f;
#pragma unroll
    for (int j = 0; j < 8; ++j) { msum2 += pm[j * 64 + lane]; ssum2 += ps[j * 64 + lane]; }
    float m  = msum2 * (1.f / 64.f);
    float va = ssum2 * (1.f / 64.f) - m * m;
    float rstd = rsqrtf(va + EPS_LN);
    float yv[64];
#pragma unroll
    for (int k = 0; k < 64; ++k)
        yv[k] = g[k] * (f2[k * 64 + lane] - m) * rstd + be[k];
    for (int j = 0; j < 8; ++j) {
        const int o = c0 + j;             // uniform
        const float* wr = &w2[o * 64];
        float a0 = 0, a1 = 0, a2 = 0, a3 = 0;
#pragma unroll
        for (int k = 0; k < 64; k += 4) {
            a0 += wr[k] * yv[k];       a1 += wr[k + 1] * yv[k + 1];
            a2 += wr[k + 2] * yv[k + 2]; a3 += wr[k + 3] * yv[k + 3];
        }
        float z = (a0 + a1) + (a2 + a3) + b2[o];
        out[(size_t)(b * 64 + o) * HW + hw] = z;
    }
}

extern "C" void kernel_launch(void* const* d_in, const int* in_sizes, int n_in,
                              void* d_out, int out_size, void* d_ws, size_t ws_size,
                              hipStream_t stream)
{
    const float* spatial  = (const float*)d_in[0];
    const float* semantic = (const float*)d_in[1];
    const float* rp_w1 = (const float*)d_in[2];
    const float* rp_b1 = (const float*)d_in[3];
    const float* rp_g  = (const float*)d_in[4];
    const float* rp_be = (const float*)d_in[5];
    const float* rp_w2 = (const float*)d_in[6];
    const float* rp_b2 = (const float*)d_in[7];
    const float* fx_w1 = (const float*)d_in[8];
    const float* fx_b1 = (const float*)d_in[9];
    const float* fx_g  = (const float*)d_in[10];
    const float* fx_be = (const float*)d_in[11];
    const float* fx_w2 = (const float*)d_in[12];
    const float* fx_b2 = (const float*)d_in[13];
    const float* op_w1 = (const float*)d_in[14];
    const float* op_b1 = (const float*)d_in[15];
    const float* op_g  = (const float*)d_in[16];
    const float* op_be = (const float*)d_in[17];
    const float* op_w2 = (const float*)d_in[18];
    const float* op_b2 = (const float*)d_in[19];
    const float* sigma = (const float*)d_in[20];

    float* ws = (float*)d_ws;
    float* px_t   = ws;
    float* sqnorm = px_t + (size_t)NPIX * 64;

    k1_range_proj<<<NBLK, 512, 0, stream>>>(
        semantic, rp_w1, rp_b1, rp_g, rp_be, rp_w2, rp_b2, px_t, sqnorm);
    k23_fused<<<NBLK, 512, 0, stream>>>(
        px_t, sqnorm, semantic, spatial,
        fx_w1, fx_b1, fx_g, fx_be, fx_w2, fx_b2,
        op_w1, op_b1, op_g, op_be, op_w2, op_b2,
        sigma, (float*)d_out);
}

// Round 7
// 194.902 us; speedup vs baseline: 1.1873x; 1.1873x over previous
//
#include <hip/hip_runtime.h>

constexpr int B = 2, C = 64, H = 112, W = 112;
constexpr int HW = H * W;          // 12544
constexpr int NPIX = B * HW;       // 25088
constexpr int NBLK = 392;          // 8 patches x 49 tiles
constexpr float EPS_LN = 1e-6f, EPS_NORM = 1e-7f;

__device__ __forceinline__ float rcp_fast(float x) { return __builtin_amdgcn_rcpf(x); }
__device__ __forceinline__ float sigmoid_f(float x) { return rcp_fast(1.f + __expf(-x)); }
// Force wave-uniformity so the compiler emits s_load for weight rows.
__device__ __forceinline__ int uni(int x) { return __builtin_amdgcn_readfirstlane(x); }

// XCD-patch swizzle: blk&7 selects (image, quadrant) -> same XCD (dispatch
// round-robins on blk%8); blk>>3 selects tile within the 7x7-tile patch.
// Patch working set ~2.4 MB fits the 4 MB per-XCD L2 -> halo overlap hits L2.
__device__ __forceinline__ void decode_blk(int blk, int& b, int& ty, int& tx) {
    int p8 = blk & 7, i = blk >> 3;
    b = p8 >> 2;
    int quad = p8 & 3;
    int lty = i / 7, ltx = i - lty * 7;
    ty = (quad >> 1) * 7 + lty;
    tx = (quad & 1) * 7 + ltx;
}

// ---------------------------------------------------------------------------
// k1: px = range_proj(semantic) -> px_t[p][64], sqnorm[p]; also transposes
// spatial -> spat_t[p][64]. 256 threads / 8x8 tile; lane = pixel.
// ---------------------------------------------------------------------------
__global__ __launch_bounds__(256) void k1_range_proj(
    const float* __restrict__ sem, const float* __restrict__ spat,
    const float* __restrict__ w1, const float* __restrict__ b1,
    const float* __restrict__ g,  const float* __restrict__ be,
    const float* __restrict__ w2, const float* __restrict__ b2,
    float* __restrict__ px_t, float* __restrict__ sqnorm, float* __restrict__ spat_t)
{
    __shared__ float f_scr[64 * 64];    // [o][pix]
    __shared__ float t_scr[64 * 65];    // [o][pix] pitch 65 (transpose buffer)
    __shared__ float pm[4 * 64], ps[4 * 64], p2[4 * 64];

    const int tid = threadIdx.x, lane = tid & 63, wv = tid >> 6;
    int b, ty, tx; decode_blk(blockIdx.x, b, ty, tx);
    const int h = ty * 8 + (lane >> 3), w = tx * 8 + (lane & 7);
    const int hw = h * W + w;

    float sv[64];
#pragma unroll
    for (int k = 0; k < 64; ++k) sv[k] = sem[(size_t)(b * 64 + k) * HW + hw];

    const int o0 = uni(wv * 16);
    float macc = 0.f, sacc = 0.f;
    for (int j = 0; j < 16; ++j) {
        const int o = o0 + j;                 // uniform -> s_load weight row
        const float* wr = &w1[o * 64];
        float a0 = 0, a1 = 0, a2 = 0, a3 = 0;
#pragma unroll
        for (int k = 0; k < 64; k += 4) {
            a0 += wr[k] * sv[k];       a1 += wr[k + 1] * sv[k + 1];
            a2 += wr[k + 2] * sv[k + 2]; a3 += wr[k + 3] * sv[k + 3];
        }
        float f = (a0 + a1) + (a2 + a3) + b1[o];
        f_scr[o * 64 + lane] = f;      // bank=lane%32: 2-way, free
        macc += f; sacc += f * f;
    }
    pm[wv * 64 + lane] = macc; ps[wv * 64 + lane] = sacc;
    __syncthreads();
    float m  = (pm[lane] + pm[64 + lane] + pm[128 + lane] + pm[192 + lane]) * (1.f / 64.f);
    float va = (ps[lane] + ps[64 + lane] + ps[128 + lane] + ps[192 + lane]) * (1.f / 64.f) - m * m;
    float rstd = rsqrtf(va + EPS_LN);

    float s[64];
#pragma unroll
    for (int k = 0; k < 64; ++k) {
        float y = g[k] * (f_scr[k * 64 + lane] - m) * rstd + be[k];
        s[k] = y * sigmoid_f(y);
    }
    float sq = 0.f;
    for (int j = 0; j < 16; ++j) {
        const int o = o0 + j;                 // uniform
        const float* wr = &w2[o * 64];
        float a0 = 0, a1 = 0, a2 = 0, a3 = 0;
#pragma unroll
        for (int k = 0; k < 64; k += 4) {
            a0 += wr[k] * s[k];        a1 += wr[k + 1] * s[k + 1];
            a2 += wr[k + 2] * s[k + 2]; a3 += wr[k + 3] * s[k + 3];
        }
        float z = (a0 + a1) + (a2 + a3) + b2[o];
        t_scr[o * 65 + lane] = z;      // bank=(o+lane)%32: conflict-free
        sq += z * z;
    }
    p2[wv * 64 + lane] = sq;
    __syncthreads();
    if (wv == 0)
        sqnorm[(size_t)b * HW + hw] = p2[lane] + p2[64 + lane] + p2[128 + lane] + p2[192 + lane];
    // transpose-out px: wave wv stores pixels o0..o0+15; lane = channel
    for (int j = 0; j < 16; ++j) {
        int ii = o0 + j;
        int hwi = (ty * 8 + (ii >> 3)) * W + tx * 8 + (ii & 7);
        px_t[((size_t)b * HW + hwi) * 64 + lane] = t_scr[lane * 65 + ii];  // (lane+ii)%32: cf
    }
    __syncthreads();   // all t_scr reads done -> reuse for spat transpose

    // spat transpose: wave wv loads channels o0..o0+15 (coalesced along pixels)
    for (int j = 0; j < 16; ++j) {
        const int c = o0 + j;
        t_scr[c * 65 + lane] = spat[(size_t)(b * 64 + c) * HW + hw];
    }
    __syncthreads();
    for (int j = 0; j < 16; ++j) {
        int ii = o0 + j;
        int hwi = (ty * 8 + (ii >> 3)) * W + tx * 8 + (ii & 7);
        spat_t[((size_t)b * HW + hwi) * 64 + lane] = t_scr[lane * 65 + ii];
    }
}

// ---------------------------------------------------------------------------
// k23: fused bilateral weights + gated fixup + normalize + neighborhood
// reduction + output_proj. 256 threads / 8x8 tile. Weights via scalar loads.
// Halo layout: element (r, c) at (r<<6) + 4*((c>>2) ^ (r&7)) + (c&3)
// -> b128 accesses at the 1KB/128B LDS floor. Both stagings are float4
// (pixel-major sources), 3136 independent coalesced loads per pass.
// ---------------------------------------------------------------------------
__global__ __launch_bounds__(256) void k23_fused(
    const float* __restrict__ px_t, const float* __restrict__ sqnorm,
    const float* __restrict__ sem,  const float* __restrict__ spat_t,
    const float* __restrict__ fw1, const float* __restrict__ fb1,
    const float* __restrict__ fg,  const float* __restrict__ fbe,
    const float* __restrict__ fw2, const float* __restrict__ fb2,
    const float* __restrict__ w1, const float* __restrict__ b1,
    const float* __restrict__ g,  const float* __restrict__ be,
    const float* __restrict__ w2, const float* __restrict__ b2,
    const float* __restrict__ sigma_, float* __restrict__ out)
{
    __shared__ __align__(16) float halo[196 * 64];      // 50176 B (aliased below)
    __shared__ __align__(16) float comb_scr[49 * 64];   // 12544 B
    __shared__ float sqn_l[196];
    __shared__ float pm[4 * 64], ps[4 * 64], pt[4 * 64];

    const int tid = threadIdx.x, lane = tid & 63, wv = tid >> 6;
    int b, ty, tx; decode_blk(blockIdx.x, b, ty, tx);
    const int h = ty * 8 + (lane >> 3), w = tx * 8 + (lane & 7);
    const int hw = h * W + w;
    const int h0 = ty * 8 - 3, w0 = tx * 8 - 3;

    // ---- phase 1: stage px halo, float4 (196 px x 16 chunks = 3136 loads) ----
    for (int i = 0; i < 13; ++i) {
        int idx = i * 256 + tid;
        if (idx < 3136) {
            int r = idx >> 4, q = idx & 15;
            int ry = (r * 2341) >> 15, rx = r - ry * 14;     // exact /14 for r<256
            int hh = h0 + ry, ww = w0 + rx;
            bool valid = (unsigned)hh < (unsigned)H && (unsigned)ww < (unsigned)W;
            float4 v = make_float4(0.f, 0.f, 0.f, 0.f);
            if (valid) v = *(const float4*)&px_t[((size_t)b * HW + hh * W + ww) * 64 + 4 * q];
            *(float4*)&halo[(r << 6) | ((4 * q) ^ ((r & 7) << 2))] = v;
        }
    }
    if (tid < 196) {
        int ry = (tid * 2341) >> 15, rx = tid - ry * 14;
        int hh = h0 + ry, ww = w0 + rx;
        bool valid = (unsigned)hh < (unsigned)H && (unsigned)ww < (unsigned)W;
        float v = 0.f;
        if (valid) v = sqnorm[(size_t)b * HW + hh * W + ww];
        sqn_l[tid] = v;
    }
    __syncthreads();

    // ---- phase 2: bilateral weights, neighbors split across waves ----
    const int rbase = (lane >> 3) * 14 + (lane & 7);
    const int rp = rbase + 45;
    const int ctr = (rp << 6) ^ ((rp & 7) << 2);
    float cv[64];
#pragma unroll
    for (int q = 0; q < 16; ++q) {
        float4 v = *(const float4*)&halo[ctr ^ (q << 2)];
        cv[4 * q] = v.x; cv[4 * q + 1] = v.y; cv[4 * q + 2] = v.z; cv[4 * q + 3] = v.w;
    }
    const float sqc = sqn_l[rp];
    const float sg_ = sigma_[0];
    const float inv2s2 = rcp_fast(2.f * sg_ * sg_);
    for (int i = 0; i < 13; ++i) {
        int n = uni(wv + 4 * i);
        if (n < 49) {
            int ryn = n / 7, rxn = n - ryn * 7;
            int dy = ryn - 3, dx = rxn - 3;
            int rn = rbase + ryn * 14 + rxn;
            int bx = (rn << 6) ^ ((rn & 7) << 2);
            float d0 = 0, d1 = 0, d2 = 0, d3 = 0;
#pragma unroll
            for (int q = 0; q < 16; ++q) {
                float4 v = *(const float4*)&halo[bx ^ (q << 2)];
                d0 += v.x * cv[4 * q];     d1 += v.y * cv[4 * q + 1];
                d2 += v.z * cv[4 * q + 2]; d3 += v.w * cv[4 * q + 3];
            }
            float dot = (d0 + d1) + (d2 + d3);
            float dist2 = fmaxf(sqn_l[rn] + sqc - 2.f * dot, 0.f);
            bool valid = (unsigned)(h + dy) < (unsigned)H && (unsigned)(w + dx) < (unsigned)W;
            float d2n = (float)(dy * dy + dx * dx);
            comb_scr[n * 64 + lane] = valid ? __expf(-(dist2 * (1.f / 128.f) + d2n * inv2s2)) : 0.f;
        }
    }
    __syncthreads();

    // ---- phase 3: gated fixup, outputs split across waves ----
    float cb[49];
#pragma unroll
    for (int n = 0; n < 49; ++n) cb[n] = comb_scr[n * 64 + lane];
    float svv[64];
#pragma unroll
    for (int k = 0; k < 64; ++k) svv[k] = sem[(size_t)(b * 64 + k) * HW + hw];
    float* f_scr = halo;                 // px halo dead after phase 2
    float macc = 0.f, sacc = 0.f;
    for (int i = 0; i < 13; ++i) {
        const int o = uni(wv + 4 * i);   // uniform -> s_load weight row
        if (o < 49) {
            const float* wr = &fw1[o * 113];
            float a0 = 0, a1 = 0, a2 = 0, a3 = 0;
#pragma unroll
            for (int k = 0; k < 48; k += 4) {
                a0 += wr[k] * cb[k];       a1 += wr[k + 1] * cb[k + 1];
                a2 += wr[k + 2] * cb[k + 2]; a3 += wr[k + 3] * cb[k + 3];
            }
            a0 += wr[48] * cb[48];
            const float* wr2 = wr + 49;
#pragma unroll
            for (int k = 0; k < 64; k += 4) {
                a0 += wr2[k] * svv[k];       a1 += wr2[k + 1] * svv[k + 1];
                a2 += wr2[k + 2] * svv[k + 2]; a3 += wr2[k + 3] * svv[k + 3];
            }
            float f = (a0 + a1) + (a2 + a3) + fb1[o];
            f_scr[o * 64 + lane] = f;
            macc += f; sacc += f * f;
        }
    }
    pm[wv * 64 + lane] = macc; ps[wv * 64 + lane] = sacc;
    __syncthreads();
    {
        float m  = (pm[lane] + pm[64 + lane] + pm[128 + lane] + pm[192 + lane]) * (1.f / 49.f);
        float va = (ps[lane] + ps[64 + lane] + ps[128 + lane] + ps[192 + lane]) * (1.f / 49.f) - m * m;
        float rstd = rsqrtf(va + EPS_LN);
        float s[49];
#pragma unroll
        for (int k = 0; k < 49; ++k) {
            float y = fg[k] * (f_scr[k * 64 + lane] - m) * rstd + fbe[k];
            s[k] = y * sigmoid_f(y);
        }
        float tacc = 0.f;
        for (int i = 0; i < 13; ++i) {
            const int o = uni(wv + 4 * i);
            if (o < 49) {
                const float* wr = &fw2[o * 49];
                float a0 = 0, a1 = 0, a2 = 0, a3 = 0;
#pragma unroll
                for (int k = 0; k < 48; k += 4) {
                    a0 += wr[k] * s[k];       a1 += wr[k + 1] * s[k + 1];
                    a2 += wr[k + 2] * s[k + 2]; a3 += wr[k + 3] * s[k + 3];
                }
                a0 += wr[48] * s[48];
                float fo = (a0 + a1) + (a2 + a3) + fb2[o];
                float gate = 1.f + sigmoid_f(fo);
                float cx = comb_scr[o * 64 + lane] * gate;
                comb_scr[o * 64 + lane] = cx;
                tacc += cx;
            }
        }
        pt[wv * 64 + lane] = tacc;
    }
    __syncthreads();   // all f_scr reads done -> halo restage is safe
    const float inv = rcp_fast(pt[lane] + pt[64 + lane] + pt[128 + lane] + pt[192 + lane] + EPS_NORM);

    // ---- phase 4: restage halo with spat_t, float4 fast path ----
    for (int i = 0; i < 13; ++i) {
        int idx = i * 256 + tid;
        if (idx < 3136) {
            int r = idx >> 4, q = idx & 15;
            int ry = (r * 2341) >> 15, rx = r - ry * 14;
            int hh = h0 + ry, ww = w0 + rx;
            bool valid = (unsigned)hh < (unsigned)H && (unsigned)ww < (unsigned)W;
            float4 v = make_float4(0.f, 0.f, 0.f, 0.f);
            if (valid) v = *(const float4*)&spat_t[((size_t)b * HW + hh * W + ww) * 64 + 4 * q];
            *(float4*)&halo[(r << 6) | ((4 * q) ^ ((r & 7) << 2))] = v;
        }
    }
    __syncthreads();

    // ---- phase 5: weighted neighborhood reduction, channels split across waves ----
    const int c0 = uni(wv * 16);
    float acc[16];
#pragma unroll
    for (int j = 0; j < 16; ++j) acc[j] = 0.f;
    for (int n = 0; n < 49; ++n) {
        int ryn = n / 7, rxn = n - ryn * 7;
        int rn = rbase + ryn * 14 + rxn;
        int bx = (rn << 6) ^ ((rn & 7) << 2);
        float cn = comb_scr[n * 64 + lane] * inv;
#pragma unroll
        for (int q = 0; q < 4; ++q) {
            float4 v = *(const float4*)&halo[bx ^ (((c0 >> 2) + q) << 2)];
            acc[4 * q]     += cn * v.x; acc[4 * q + 1] += cn * v.y;
            acc[4 * q + 2] += cn * v.z; acc[4 * q + 3] += cn * v.w;
        }
    }
    __syncthreads();   // halo reads done -> av/f2 aliases safe

    // ---- phase 6: output_proj ----
    float* av = halo;                 // [c][pix] 64x64
    float* f2 = halo + 4096;          // [o][pix] 64x64
    for (int j = 0; j < 16; ++j) av[(c0 + j) * 64 + lane] = acc[j];
    __syncthreads();
    float xv[64];
#pragma unroll
    for (int k = 0; k < 64; ++k) xv[k] = av[k * 64 + lane];
    float macc2 = 0.f, sacc2 = 0.f;
    for (int j = 0; j < 16; ++j) {
        const int o = c0 + j;             // uniform
        const float* wr = &w1[o * 64];
        float a0 = 0, a1 = 0, a2 = 0, a3 = 0;
#pragma unroll
        for (int k = 0; k < 64; k += 4) {
            a0 += wr[k] * xv[k];       a1 += wr[k + 1] * xv[k + 1];
            a2 += wr[k + 2] * xv[k + 2]; a3 += wr[k + 3] * xv[k + 3];
        }
        float f = (a0 + a1) + (a2 + a3) + b1[o];
        f2[o * 64 + lane] = f;
        macc2 += f; sacc2 += f * f;
    }
    pm[wv * 64 + lane] = macc2; ps[wv * 64 + lane] = sacc2;
    __syncthreads();
    float m  = (pm[lane] + pm[64 + lane] + pm[128 + lane] + pm[192 + lane]) * (1.f / 64.f);
    float va = (ps[lane] + ps[64 + lane] + ps[128 + lane] + ps[192 + lane]) * (1.f / 64.f) - m * m;
    float rstd = rsqrtf(va + EPS_LN);
    float yv[64];
#pragma unroll
    for (int k = 0; k < 64; ++k)
        yv[k] = g[k] * (f2[k * 64 + lane] - m) * rstd + be[k];
    for (int j = 0; j < 16; ++j) {
        const int o = c0 + j;             // uniform
        const float* wr = &w2[o * 64];
        float a0 = 0, a1 = 0, a2 = 0, a3 = 0;
#pragma unroll
        for (int k = 0; k < 64; k += 4) {
            a0 += wr[k] * yv[k];       a1 += wr[k + 1] * yv[k + 1];
            a2 += wr[k + 2] * yv[k + 2]; a3 += wr[k + 3] * yv[k + 3];
        }
        float z = (a0 + a1) + (a2 + a3) + b2[o];
        out[(size_t)(b * 64 + o) * HW + hw] = z;
    }
}

extern "C" void kernel_launch(void* const* d_in, const int* in_sizes, int n_in,
                              void* d_out, int out_size, void* d_ws, size_t ws_size,
                              hipStream_t stream)
{
    const float* spatial  = (const float*)d_in[0];
    const float* semantic = (const float*)d_in[1];
    const float* rp_w1 = (const float*)d_in[2];
    const float* rp_b1 = (const float*)d_in[3];
    const float* rp_g  = (const float*)d_in[4];
    const float* rp_be = (const float*)d_in[5];
    const float* rp_w2 = (const float*)d_in[6];
    const float* rp_b2 = (const float*)d_in[7];
    const float* fx_w1 = (const float*)d_in[8];
    const float* fx_b1 = (const float*)d_in[9];
    const float* fx_g  = (const float*)d_in[10];
    const float* fx_be = (const float*)d_in[11];
    const float* fx_w2 = (const float*)d_in[12];
    const float* fx_b2 = (const float*)d_in[13];
    const float* op_w1 = (const float*)d_in[14];
    const float* op_b1 = (const float*)d_in[15];
    const float* op_g  = (const float*)d_in[16];
    const float* op_be = (const float*)d_in[17];
    const float* op_w2 = (const float*)d_in[18];
    const float* op_b2 = (const float*)d_in[19];
    const float* sigma = (const float*)d_in[20];

    float* ws = (float*)d_ws;
    float* px_t   = ws;
    float* sqnorm = px_t + (size_t)NPIX * 64;
    float* spat_t = sqnorm + (size_t)NPIX;

    k1_range_proj<<<NBLK, 256, 0, stream>>>(
        semantic, spatial, rp_w1, rp_b1, rp_g, rp_be, rp_w2, rp_b2,
        px_t, sqnorm, spat_t);
    k23_fused<<<NBLK, 256, 0, stream>>>(
        px_t, sqnorm, semantic, spat_t,
        fx_w1, fx_b1, fx_g, fx_be, fx_w2, fx_b2,
        op_w1, op_b1, op_g, op_be, op_w2, op_b2,
        sigma, (float*)d_out);
}